// Round 1
// 240.299 us; speedup vs baseline: 1.0471x; 1.0471x over previous
//
#include <hip/hip_runtime.h>
#include <hip/hip_bf16.h>

// ModuleCorrelation as implicit GEMM on MFMA (bf16 in, fp32 acc), v4.
// out[b, dy*9+dx, y, x] = (1/64) sum_c F[b,c,y,x] * S[b,c,y+dy-4,x+dx-4]
//
// v4 changes vs v3 (theory: v3 was latency-bound at 2 waves/SIMD because
// acc[2][9][2] = 144 unified VGPR/AGPR of accumulator):
//   - dy split into 3 groups of 3: acc[2][3][2] = 48 regs, launch_bounds(256,4)
//     -> 4 waves/SIMD, 3x more waves device-wide (23040).
//   - epilogue: float4 LDS reads + float4 global stores (2 rounds, not 7),
//     per-wave LDS 2.16 KB (EST=20 stride keeps conflicts <=2-way).
//   - fill_frame: zero only the 2.1 MB pad frame, not the whole 33.6 MB Sp.
//   - conv_both: fused F+S conversion, both tile loads in flight, one barrier.

#define WW   320
#define HH   192
#define CC   64
#define HWSZ (HH * WW)
#define NB   4
#define PW   328   // WW + 8
#define PH   200   // HH + 8
#define NDISP 81
#define EST  18    // v3 epilogue stride (kept for fallback kernel)
#define ESTV 20    // v4 epilogue stride: mult of 4 for b128, breaks bank conflicts

typedef __attribute__((ext_vector_type(8))) short bf16x8_t;   // 8 bf16 (4 VGPRs)
typedef __attribute__((ext_vector_type(4))) float f32x4_t;    // 4 fp32

static __device__ __forceinline__ unsigned short f2bf(float f) {
    unsigned int u = __float_as_uint(f);
    u += 0x7fffu + ((u >> 16) & 1u);   // round-nearest-even
    return (unsigned short)(u >> 16);
}

// ---------------- kernel 1 (v4): zero ONLY the pad frame of Sp ----------------
// Interior rows 4..195 x cols 4..323 are fully overwritten by conv_both.
// Frame per b: rows {0..3,196..199} x PW  +  rows 4..195 x cols {0..3,324..327}
//   = 4*328*2 + 192*8 = 4160 px, 8 uint4 each. Total 4*4160*8 = 133120 uint4.
__global__ __launch_bounds__(256) void fill_frame(uint4* __restrict__ Sp) {
    int i = blockIdx.x * 256 + threadIdx.x;
    if (i >= NB * 4160 * 8) return;
    int b  = i / (4160 * 8);
    int r  = i % (4160 * 8);
    int px = r >> 3;
    int v  = r & 7;
    int row, colp;
    if (px < 2624) {                       // top/bottom strips, full width
        int strip = px / 1312;             // 0=top rows 0..3, 1=bottom rows 196..199
        int pp    = px % 1312;
        row  = (strip ? 196 : 0) + pp / 328;
        colp = pp % 328;
    } else {                               // left/right 4-col strips, rows 4..195
        int t  = px - 2624;                // 0..1535
        row  = 4 + (t >> 3);
        int tt = t & 7;
        colp = (tt < 4) ? tt : (320 + tt); // 0..3 or 324..327
    }
    uint4 z; z.x = 0u; z.y = 0u; z.z = 0u; z.w = 0u;
    Sp[(((size_t)b * PH + row) * PW + colp) * 8 + v] = z;
}

// ---------------- kernel 2 (v4): fused F->Fc and S->Sp conversion ----------------
// Both 64x64 fp32 tiles loaded into separate LDS arrays before ONE barrier so
// all 32 global loads/thread are in flight together.
__global__ __launch_bounds__(256) void conv_both(const float* __restrict__ F,
                                                 const float* __restrict__ S,
                                                 unsigned short* __restrict__ Fc,
                                                 unsigned short* __restrict__ Sp) {
    __shared__ float ta[64][65];
    __shared__ float tb[64][65];
    const int tx = threadIdx.x;      // 0..63 (x)
    const int ty = threadIdx.y;      // 0..3  (c-chunk)
    const int x0 = blockIdx.x * 64;
    const int y  = blockIdx.y;
    const int b  = blockIdx.z;

    const float* fsrc = F + (size_t)b * CC * HWSZ + (size_t)y * WW + x0 + tx;
    const float* ssrc = S + (size_t)b * CC * HWSZ + (size_t)y * WW + x0 + tx;
#pragma unroll
    for (int i = 0; i < 16; ++i) {
        int c = ty * 16 + i;
        ta[c][tx] = fsrc[(size_t)c * HWSZ];
        tb[c][tx] = ssrc[(size_t)c * HWSZ];
    }
    __syncthreads();

    const int t  = ty * 64 + tx;
    const int xx = t >> 2;
    const int cg = (t & 3) * 16;

    {   // F -> Fc [H][W][C]
        unsigned short tmp[16];
#pragma unroll
        for (int i = 0; i < 16; ++i) tmp[i] = f2bf(ta[cg + i][xx]);
        unsigned short* dst = Fc + (((size_t)b * HH + y) * WW + (x0 + xx)) * CC + cg;
        uint4 v;
        v.x = (unsigned)tmp[0]  | ((unsigned)tmp[1]  << 16);
        v.y = (unsigned)tmp[2]  | ((unsigned)tmp[3]  << 16);
        v.z = (unsigned)tmp[4]  | ((unsigned)tmp[5]  << 16);
        v.w = (unsigned)tmp[6]  | ((unsigned)tmp[7]  << 16);
        *(uint4*)dst = v;
        v.x = (unsigned)tmp[8]  | ((unsigned)tmp[9]  << 16);
        v.y = (unsigned)tmp[10] | ((unsigned)tmp[11] << 16);
        v.z = (unsigned)tmp[12] | ((unsigned)tmp[13] << 16);
        v.w = (unsigned)tmp[14] | ((unsigned)tmp[15] << 16);
        *(uint4*)(dst + 8) = v;
    }
    {   // S -> Sp [PH][PW][C], +4 offset
        unsigned short tmp[16];
#pragma unroll
        for (int i = 0; i < 16; ++i) tmp[i] = f2bf(tb[cg + i][xx]);
        unsigned short* dst = Sp + (((size_t)b * PH + (y + 4)) * PW + (x0 + xx + 4)) * CC + cg;
        uint4 v;
        v.x = (unsigned)tmp[0]  | ((unsigned)tmp[1]  << 16);
        v.y = (unsigned)tmp[2]  | ((unsigned)tmp[3]  << 16);
        v.z = (unsigned)tmp[4]  | ((unsigned)tmp[5]  << 16);
        v.w = (unsigned)tmp[6]  | ((unsigned)tmp[7]  << 16);
        *(uint4*)dst = v;
        v.x = (unsigned)tmp[8]  | ((unsigned)tmp[9]  << 16);
        v.y = (unsigned)tmp[10] | ((unsigned)tmp[11] << 16);
        v.z = (unsigned)tmp[12] | ((unsigned)tmp[13] << 16);
        v.w = (unsigned)tmp[14] | ((unsigned)tmp[15] << 16);
        *(uint4*)(dst + 8) = v;
    }
}

// ---------------- kernel 3: MFMA correlation v4 (dy-split x3, YB=2) ----------------
// Wave owns (b, y-pair, 16-px x-tile, dy-group of 3). acc[2][3][2] = 48 regs.
// 16 b128 B-loads feed 24 MFMAs. XCD slab swizzle keeps a 24-row y-slab per XCD;
// within a (b,pql) chunk the working set (Fc 8 rows + Sp ~17 rows) is ~2 MB < L2.
__global__ __launch_bounds__(256, 4)
void corr_mfma_v4(const unsigned short* __restrict__ Fc,
                  const unsigned short* __restrict__ Sp,
                  float* __restrict__ out) {
    __shared__ float ebuf[4][27 * ESTV];   // 4 waves x 2.16 KB = 8.64 KB

    const int tid  = threadIdx.x;
    const int wave = tid >> 6;
    const int lane = tid & 63;
    const int q    = lane >> 4;
    const int col  = lane & 15;

    // ---- decode: 5760 blocks = 8 xcd x 4 b x 3 pql x 3 g x 20 xt
    const int i    = blockIdx.x;
    const int xcd  = i & 7;
    const int j    = i >> 3;              // 0..719
    const int b    = j / 180;
    const int r180 = j % 180;
    const int pql  = r180 / 60;           // 0..2
    const int r60  = r180 % 60;
    const int g    = r60 / 20;            // dy-group 0..2
    const int xt   = r60 % 20;
    const int pq   = xcd * 3 + pql;       // 0..23
    const int yp   = pq * 4 + wave;       // ypair 0..95
    const int y0   = yp * 2;
    const int x0   = xt * 16;
    const int d0   = g * 3;               // dy base of this group

    // ---- A fragments for both y rows: per-lane contiguous b128 from Fc
    const unsigned short* fc =
        Fc + (((size_t)b * HH + y0) * WW + (x0 + col)) * CC + q * 8;
    const bf16x8_t a00 = *(const bf16x8_t*)(fc);                 // y0, k 0..31
    const bf16x8_t a01 = *(const bf16x8_t*)(fc + 32);            // y0, k 32..63
    const bf16x8_t a10 = *(const bf16x8_t*)(fc + (size_t)WW * CC);      // y0+1
    const bf16x8_t a11 = *(const bf16x8_t*)(fc + (size_t)WW * CC + 32);

    f32x4_t acc[2][3][2];
#pragma unroll
    for (int p = 0; p < 2; ++p)
#pragma unroll
        for (int d = 0; d < 3; ++d)
#pragma unroll
            for (int nt = 0; nt < 2; ++nt)
#pragma unroll
                for (int k = 0; k < 4; ++k) acc[p][d][nt][k] = 0.f;

    // ---- padded rows y0+d0 .. y0+d0+3 feed both y-parts (share 2/4 rows fully)
#pragma unroll
    for (int rr = 0; rr < 4; ++rr) {
        const unsigned short* srow = Sp + ((size_t)b * PH + (y0 + d0 + rr)) * PW * CC;
#pragma unroll
        for (int nt = 0; nt < 2; ++nt) {
            int xp = x0 + col + 16 * nt;
            xp = xp > (PW - 1) ? (PW - 1) : xp;   // clamped lanes never enter the band
            const unsigned short* p = srow + (size_t)xp * CC + q * 8;
            const bf16x8_t b0 = *(const bf16x8_t*)(p);
            const bf16x8_t b1 = *(const bf16x8_t*)(p + 32);
            if (rr < 3) {
                acc[0][rr][nt] = __builtin_amdgcn_mfma_f32_16x16x32_bf16(a00, b0, acc[0][rr][nt], 0, 0, 0);
                acc[0][rr][nt] = __builtin_amdgcn_mfma_f32_16x16x32_bf16(a01, b1, acc[0][rr][nt], 0, 0, 0);
            }
            if (rr >= 1) {
                acc[1][rr - 1][nt] = __builtin_amdgcn_mfma_f32_16x16x32_bf16(a10, b0, acc[1][rr - 1][nt], 0, 0, 0);
                acc[1][rr - 1][nt] = __builtin_amdgcn_mfma_f32_16x16x32_bf16(a11, b1, acc[1][rr - 1][nt], 0, 0, 0);
            }
        }
    }

    // ---- epilogue per y-part: band-extract -> per-wave LDS -> float4 stores
    const float scale = 1.0f / 64.0f;
    float* my = ebuf[wave];
#pragma unroll
    for (int p = 0; p < 2; ++p) {
#pragma unroll
        for (int dyi = 0; dyi < 3; ++dyi)
#pragma unroll
            for (int nt = 0; nt < 2; ++nt)
#pragma unroll
                for (int k = 0; k < 4; ++k) {
                    int m  = 4 * q + k;
                    int dx = col + 16 * nt - m;
                    if (dx >= 0 && dx <= 8)
                        my[(dyi * 9 + dx) * ESTV + m] = acc[p][dyi][nt][k] * scale;
                }
        // in-wave DS ordering: per-wave staging needs no barrier
        float* ob = out + ((size_t)b * NDISP + d0 * 9) * HWSZ + (size_t)(y0 + p) * WW + x0;
        // 27 disp-rows x 16 floats = 108 float4, 2 rounds
#pragma unroll
        for (int rnd = 0; rnd < 2; ++rnd) {
            int idx = rnd * 64 + lane;
            if (idx < 108) {
                int d  = idx >> 2;
                int m4 = (idx & 3) * 4;
                *(float4*)(ob + (size_t)d * HWSZ + m4) = *(const float4*)(my + d * ESTV + m4);
            }
        }
    }
}

// ---------------- fallback: full-buffer zero (mid path) ----------------
__global__ __launch_bounds__(256) void fill_zero(uint4* __restrict__ p, int n4) {
    int i = blockIdx.x * 256 + threadIdx.x;
    if (i < n4) {
        uint4 z; z.x = 0u; z.y = 0u; z.z = 0u; z.w = 0u;
        p[i] = z;
    }
}

// ---------------- fallback: S fp32 CHW -> bf16 (H+8)(W+8)C, +4 offset ----------------
__global__ __launch_bounds__(256) void conv_pad(const float* __restrict__ S,
                                                unsigned short* __restrict__ Sp) {
    __shared__ float tile[64][65];
    const int tx = threadIdx.x;
    const int ty = threadIdx.y;
    const int x0 = blockIdx.x * 64;
    const int y  = blockIdx.y;
    const int b  = blockIdx.z;

    const float* src = S + (size_t)b * CC * HWSZ + (size_t)y * WW + x0 + tx;
#pragma unroll
    for (int i = 0; i < 16; ++i) {
        int c = ty * 16 + i;
        tile[c][tx] = src[(size_t)c * HWSZ];
    }
    __syncthreads();

    const int t  = ty * 64 + tx;
    const int xx = t >> 2;
    const int cg = (t & 3) * 16;
    unsigned short tmp[16];
#pragma unroll
    for (int i = 0; i < 16; ++i) tmp[i] = f2bf(tile[cg + i][xx]);

    unsigned short* dst = Sp + (((size_t)b * PH + (y + 4)) * PW + (x0 + xx + 4)) * CC + cg;
    uint4 v;
    v.x = (unsigned)tmp[0]  | ((unsigned)tmp[1]  << 16);
    v.y = (unsigned)tmp[2]  | ((unsigned)tmp[3]  << 16);
    v.z = (unsigned)tmp[4]  | ((unsigned)tmp[5]  << 16);
    v.w = (unsigned)tmp[6]  | ((unsigned)tmp[7]  << 16);
    *(uint4*)dst = v;
    v.x = (unsigned)tmp[8]  | ((unsigned)tmp[9]  << 16);
    v.y = (unsigned)tmp[10] | ((unsigned)tmp[11] << 16);
    v.z = (unsigned)tmp[12] | ((unsigned)tmp[13] << 16);
    v.w = (unsigned)tmp[14] | ((unsigned)tmp[15] << 16);
    *(uint4*)(dst + 8) = v;
}

// ---------------- mid fallback: round-2 MFMA kernel (F fp32 direct) ----------------
__global__ __launch_bounds__(256) void corr_mfma(const float* __restrict__ F,
                                                 const unsigned short* __restrict__ Sp,
                                                 float* __restrict__ out) {
    __shared__ float lds[4][NDISP * 16];
    const int tid  = threadIdx.x;
    const int wave = tid >> 6;
    const int lane = tid & 63;
    const int q    = lane >> 4;
    const int col  = lane & 15;
    const int wid = blockIdx.x * 4 + wave;
    const int xt  = wid % 20;
    const int y   = (wid / 20) % HH;
    const int b   = wid / (20 * HH);
    const int x0  = xt * 16;

    bf16x8_t a0, a1;
    const float* fb = F + (size_t)b * CC * HWSZ + (size_t)y * WW + x0 + col;
#pragma unroll
    for (int j = 0; j < 8; ++j) {
        a0[j] = (short)f2bf(fb[(size_t)(q * 8 + j) * HWSZ]);
        a1[j] = (short)f2bf(fb[(size_t)(32 + q * 8 + j) * HWSZ]);
    }
    f32x4_t acc[9][2];
#pragma unroll
    for (int i = 0; i < 9; ++i)
#pragma unroll
        for (int nt = 0; nt < 2; ++nt)
#pragma unroll
            for (int r = 0; r < 4; ++r) acc[i][nt][r] = 0.f;
#pragma unroll
    for (int dyi = 0; dyi < 9; ++dyi) {
        const unsigned short* srow = Sp + ((size_t)b * PH + (y + dyi)) * PW * CC;
#pragma unroll
        for (int nt = 0; nt < 2; ++nt) {
            int xp = x0 + col + 16 * nt;
            xp = xp > (PW - 1) ? (PW - 1) : xp;
            const unsigned short* p = srow + (size_t)xp * CC + q * 8;
            bf16x8_t b0 = *(const bf16x8_t*)(p);
            bf16x8_t b1 = *(const bf16x8_t*)(p + 32);
            acc[dyi][nt] = __builtin_amdgcn_mfma_f32_16x16x32_bf16(a0, b0, acc[dyi][nt], 0, 0, 0);
            acc[dyi][nt] = __builtin_amdgcn_mfma_f32_16x16x32_bf16(a1, b1, acc[dyi][nt], 0, 0, 0);
        }
    }
    float* my = lds[wave];
    const float scale = 1.0f / 64.0f;
#pragma unroll
    for (int dyi = 0; dyi < 9; ++dyi)
#pragma unroll
        for (int nt = 0; nt < 2; ++nt)
#pragma unroll
            for (int r = 0; r < 4; ++r) {
                int m  = 4 * q + r;
                int dx = col + 16 * nt - m;
                if (dx >= 0 && dx <= 8)
                    my[(dyi * 9 + dx) * 16 + m] = acc[dyi][nt][r] * scale;
            }
    __syncthreads();
    float* ob = out + (size_t)b * NDISP * HWSZ + (size_t)y * WW + x0;
#pragma unroll
    for (int rnd = 0; rnd < 21; ++rnd) {
        int idx = rnd * 64 + lane;
        if (rnd < 20 || idx < NDISP * 16) {
            int d = idx >> 4, m = idx & 15;
            ob[(size_t)d * HWSZ + m] = my[idx];
        }
    }
}

// ---------------- last-resort fallback: direct fp32 kernel ----------------
#define MDV      4
#define TILE_X   64
#define TILE_Y   8
#define CH_STAGE 4
#define LDS_ROWS (TILE_Y + 2 * MDV)
#define LDS_COLS (TILE_X + 2 * MDV)

__global__ __launch_bounds__(256, 2)
void corr_direct(const float* __restrict__ first,
                 const float* __restrict__ second,
                 float* __restrict__ out) {
    const int C = 64, H = HH, W = WW;
    const int HW = H * W;
    __shared__ float lds[CH_STAGE][LDS_ROWS * LDS_COLS];
    const int tx = threadIdx.x, ty = threadIdx.y;
    const int tid = ty * 32 + tx;
    const int x_tile = blockIdx.x * TILE_X;
    const int y_tile = blockIdx.y * TILE_Y;
    const int b = blockIdx.z;
    const int x0 = x_tile + 2 * tx;
    const int y  = y_tile + ty;
    const float* fst_b = first  + (size_t)b * C * HW;
    const float* sec_b = second + (size_t)b * C * HW;
    float acc[NDISP][2];
#pragma unroll
    for (int d = 0; d < NDISP; ++d) { acc[d][0] = 0.f; acc[d][1] = 0.f; }
    for (int cb = 0; cb < C; cb += CH_STAGE) {
        __syncthreads();
        const int total = CH_STAGE * LDS_ROWS * LDS_COLS;
#pragma unroll
        for (int k = 0; k < total / 256; ++k) {
            int i = tid + k * 256;
            int c   = i / (LDS_ROWS * LDS_COLS);
            int rem = i - c * (LDS_ROWS * LDS_COLS);
            int r   = rem / LDS_COLS;
            int cl  = rem - r * LDS_COLS;
            int gy = y_tile - MDV + r;
            int gx = x_tile - MDV + cl;
            float v = 0.f;
            if ((unsigned)gy < (unsigned)H && (unsigned)gx < (unsigned)W)
                v = sec_b[(size_t)(cb + c) * HW + gy * W + gx];
            lds[c][rem] = v;
        }
        __syncthreads();
#pragma unroll
        for (int cl = 0; cl < CH_STAGE; ++cl) {
            const int c = cb + cl;
            const float2 f = *(const float2*)&fst_b[(size_t)c * HW + y * W + x0];
#pragma unroll
            for (int r = 0; r < 9; ++r) {
                const float* row = &lds[cl][(ty + r) * LDS_COLS + 2 * tx];
                float w[10];
#pragma unroll
                for (int k = 0; k < 5; ++k) {
                    float2 t2 = *(const float2*)&row[2 * k];
                    w[2 * k] = t2.x; w[2 * k + 1] = t2.y;
                }
#pragma unroll
                for (int dx = 0; dx < 9; ++dx) {
                    acc[r * 9 + dx][0] += f.x * w[dx];
                    acc[r * 9 + dx][1] += f.y * w[dx + 1];
                }
            }
        }
    }
    const float scale = 1.0f / 64.0f;
    float* out_b = out + (size_t)b * NDISP * HW;
#pragma unroll
    for (int d = 0; d < NDISP; ++d) {
        float2 o;
        o.x = acc[d][0] * scale;
        o.y = acc[d][1] * scale;
        *(float2*)&out_b[(size_t)d * HW + y * W + x0] = o;
    }
}

extern "C" void kernel_launch(void* const* d_in, const int* in_sizes, int n_in,
                              void* d_out, int out_size, void* d_ws, size_t ws_size,
                              hipStream_t stream) {
    const float* tenFirst  = (const float*)d_in[0];
    const float* tenSecond = (const float*)d_in[1];
    float* out = (float*)d_out;

    const size_t sp_bytes = (size_t)NB * PH * PW * CC * 2;   // 33.6 MB bf16 padded S
    const size_t fc_bytes = (size_t)NB * HH * WW * CC * 2;   // 31.5 MB bf16 F

    if (ws_size >= sp_bytes + fc_bytes) {
        unsigned short* Sp = (unsigned short*)d_ws;
        unsigned short* Fc = (unsigned short*)((char*)d_ws + sp_bytes);
        fill_frame<<<520, 256, 0, stream>>>((uint4*)Sp);
        conv_both<<<dim3(WW / 64, HH, NB), dim3(64, 4), 0, stream>>>(tenFirst, tenSecond, Fc, Sp);
        corr_mfma_v4<<<5760, 256, 0, stream>>>(Fc, Sp, out);
    } else if (ws_size >= sp_bytes) {
        unsigned short* Sp = (unsigned short*)d_ws;
        const int n4 = (int)(sp_bytes / 16);
        fill_zero<<<(n4 + 255) / 256, 256, 0, stream>>>((uint4*)Sp, n4);
        conv_pad<<<dim3(WW / 64, HH, NB), dim3(64, 4), 0, stream>>>(tenSecond, Sp);
        corr_mfma<<<NB * HH * 20 / 4, 256, 0, stream>>>(tenFirst, Sp, out);
    } else {
        corr_direct<<<dim3(WW / TILE_X, HH / TILE_Y, NB), dim3(32, 8), 0, stream>>>(
            tenFirst, tenSecond, out);
    }
}

// Round 2
// 234.422 us; speedup vs baseline: 1.0733x; 1.0251x over previous
//
#include <hip/hip_runtime.h>
#include <hip/hip_bf16.h>

// ModuleCorrelation as implicit GEMM on MFMA (bf16 in, fp32 acc), v5.
// out[b, dy*9+dx, y, x] = (1/64) sum_c F[b,c,y,x] * S[b,c,y+dy-4,x+dx-4]
//
// v5 changes vs v4 (theory: conv_both was the slowest kernel at 65us,
// latency-bound: 4 blocks/CU LDS cap + 32 scalar dword loads/thread):
//   - conv_both: float4 global loads (8 per thread, all in flight up front),
//     ONE shared 64x65 tile reused for F then S (16.6 KB -> 8 blocks/CU LDS
//     cap), launch_bounds(256,6), inline pack (no 16-short temp array).
//   - pad-frame zeroing folded into conv_both's first 520 blocks; the
//     fill_frame launch is gone.
//   - corr_mfma_v4 unchanged (94 -> <65us after the round-1 dy-split).

#define WW   320
#define HH   192
#define CC   64
#define HWSZ (HH * WW)
#define NB   4
#define PW   328   // WW + 8
#define PH   200   // HH + 8
#define NDISP 81
#define ESTV 20    // epilogue stride: mult of 4 for b128, breaks bank conflicts

typedef __attribute__((ext_vector_type(8))) short bf16x8_t;   // 8 bf16 (4 VGPRs)
typedef __attribute__((ext_vector_type(4))) float f32x4_t;    // 4 fp32

static __device__ __forceinline__ unsigned short f2bf(float f) {
    unsigned int u = __float_as_uint(f);
    u += 0x7fffu + ((u >> 16) & 1u);   // round-nearest-even
    return (unsigned short)(u >> 16);
}

static __device__ __forceinline__ unsigned pack2(float a, float b) {
    return (unsigned)f2bf(a) | ((unsigned)f2bf(b) << 16);
}

// ---------------- kernel 1 (v5): fused F->Fc, S->Sp conversion + frame zero ----
// Block: one y row, 64 x, all 64 c, both inputs sequentially through ONE LDS
// tile. All 8 float4 loads issued up front (F-unpack waits vmcnt(4), S loads
// stay in flight across the F convert phase). First 520 blocks also zero the
// 2.1 MB pad frame of Sp (disjoint addresses, no ordering hazard).
__global__ __launch_bounds__(256, 6)
void conv_both(const float* __restrict__ F,
               const float* __restrict__ S,
               unsigned short* __restrict__ Fc,
               unsigned short* __restrict__ Sp) {
    __shared__ float ta[64][65];           // 16.64 KB
    const int t  = threadIdx.x;            // 0..255
    const int x0 = blockIdx.x * 64;
    const int y  = blockIdx.y;
    const int b  = blockIdx.z;

    // ---- pad-frame zeroing (520 of 3840 blocks, one uint4 per thread)
    const int blk = (b * HH + y) * (WW / 64) + blockIdx.x;
    const int gid = blk * 256 + t;
    if (gid < NB * 4160 * 8) {
        int bb = gid / (4160 * 8);
        int r  = gid % (4160 * 8);
        int px = r >> 3;
        int v  = r & 7;
        int row, colp;
        if (px < 2624) {                       // top/bottom strips, full width
            int strip = px / 1312;
            int pp    = px % 1312;
            row  = (strip ? 196 : 0) + pp / 328;
            colp = pp % 328;
        } else {                               // left/right 4-col strips
            int tt2 = px - 2624;
            row  = 4 + (tt2 >> 3);
            int tt = tt2 & 7;
            colp = (tt < 4) ? tt : (320 + tt);
        }
        uint4 z; z.x = 0u; z.y = 0u; z.z = 0u; z.w = 0u;
        *(uint4*)((unsigned short*)Sp + ((((size_t)bb * PH + row) * PW + colp) * 8 + v) * 8) = z;
    }

    // ---- issue all 8 float4 loads up front
    const int x4 = t & 15;                 // float4 column 0..15
    const int c0 = t >> 4;                 // base channel 0..15
    const float* fsrc = F + (size_t)b * CC * HWSZ + (size_t)y * WW + x0 + 4 * x4;
    const float* ssrc = S + (size_t)b * CC * HWSZ + (size_t)y * WW + x0 + 4 * x4;
    float4 vF[4], vS[4];
#pragma unroll
    for (int k = 0; k < 4; ++k)
        vF[k] = *(const float4*)(fsrc + (size_t)(c0 + 16 * k) * HWSZ);
#pragma unroll
    for (int k = 0; k < 4; ++k)
        vS[k] = *(const float4*)(ssrc + (size_t)(c0 + 16 * k) * HWSZ);

    // ---- unpack F -> LDS (scalar writes: bank (c+4*x4+j)%32, 2-way = free)
#pragma unroll
    for (int k = 0; k < 4; ++k) {
        int c = c0 + 16 * k;
        ta[c][4 * x4 + 0] = vF[k].x;
        ta[c][4 * x4 + 1] = vF[k].y;
        ta[c][4 * x4 + 2] = vF[k].z;
        ta[c][4 * x4 + 3] = vF[k].w;
    }
    __syncthreads();

    // ---- convert F -> Fc [H][W][C]
    const int xx = t >> 2;                 // x within tile 0..15 -> wait, 0..63
    const int cg = (t & 3) * 16;           // channel group base
    {
        unsigned short* dst = Fc + (((size_t)b * HH + y) * WW + (x0 + xx)) * CC + cg;
        uint4 w;
        w.x = pack2(ta[cg + 0][xx],  ta[cg + 1][xx]);
        w.y = pack2(ta[cg + 2][xx],  ta[cg + 3][xx]);
        w.z = pack2(ta[cg + 4][xx],  ta[cg + 5][xx]);
        w.w = pack2(ta[cg + 6][xx],  ta[cg + 7][xx]);
        *(uint4*)dst = w;
        w.x = pack2(ta[cg + 8][xx],  ta[cg + 9][xx]);
        w.y = pack2(ta[cg + 10][xx], ta[cg + 11][xx]);
        w.z = pack2(ta[cg + 12][xx], ta[cg + 13][xx]);
        w.w = pack2(ta[cg + 14][xx], ta[cg + 15][xx]);
        *(uint4*)(dst + 8) = w;
    }
    __syncthreads();

    // ---- unpack S -> same LDS tile
#pragma unroll
    for (int k = 0; k < 4; ++k) {
        int c = c0 + 16 * k;
        ta[c][4 * x4 + 0] = vS[k].x;
        ta[c][4 * x4 + 1] = vS[k].y;
        ta[c][4 * x4 + 2] = vS[k].z;
        ta[c][4 * x4 + 3] = vS[k].w;
    }
    __syncthreads();

    // ---- convert S -> Sp [PH][PW][C], +4 offset
    {
        unsigned short* dst = Sp + (((size_t)b * PH + (y + 4)) * PW + (x0 + xx + 4)) * CC + cg;
        uint4 w;
        w.x = pack2(ta[cg + 0][xx],  ta[cg + 1][xx]);
        w.y = pack2(ta[cg + 2][xx],  ta[cg + 3][xx]);
        w.z = pack2(ta[cg + 4][xx],  ta[cg + 5][xx]);
        w.w = pack2(ta[cg + 6][xx],  ta[cg + 7][xx]);
        *(uint4*)dst = w;
        w.x = pack2(ta[cg + 8][xx],  ta[cg + 9][xx]);
        w.y = pack2(ta[cg + 10][xx], ta[cg + 11][xx]);
        w.z = pack2(ta[cg + 12][xx], ta[cg + 13][xx]);
        w.w = pack2(ta[cg + 14][xx], ta[cg + 15][xx]);
        *(uint4*)(dst + 8) = w;
    }
}

// ---------------- kernel 2: MFMA correlation v4 (dy-split x3, YB=2) ----------------
// Wave owns (b, y-pair, 16-px x-tile, dy-group of 3). acc[2][3][2] = 48 regs.
// 16 b128 B-loads feed 24 MFMAs. XCD slab swizzle keeps a 24-row y-slab per XCD.
__global__ __launch_bounds__(256, 4)
void corr_mfma_v4(const unsigned short* __restrict__ Fc,
                  const unsigned short* __restrict__ Sp,
                  float* __restrict__ out) {
    __shared__ float ebuf[4][27 * ESTV];   // 4 waves x 2.16 KB = 8.64 KB

    const int tid  = threadIdx.x;
    const int wave = tid >> 6;
    const int lane = tid & 63;
    const int q    = lane >> 4;
    const int col  = lane & 15;

    // ---- decode: 5760 blocks = 8 xcd x 4 b x 3 pql x 3 g x 20 xt
    const int i    = blockIdx.x;
    const int xcd  = i & 7;
    const int j    = i >> 3;              // 0..719
    const int b    = j / 180;
    const int r180 = j % 180;
    const int pql  = r180 / 60;           // 0..2
    const int r60  = r180 % 60;
    const int g    = r60 / 20;            // dy-group 0..2
    const int xt   = r60 % 20;
    const int pq   = xcd * 3 + pql;       // 0..23
    const int yp   = pq * 4 + wave;       // ypair 0..95
    const int y0   = yp * 2;
    const int x0   = xt * 16;
    const int d0   = g * 3;               // dy base of this group

    // ---- A fragments for both y rows: per-lane contiguous b128 from Fc
    const unsigned short* fc =
        Fc + (((size_t)b * HH + y0) * WW + (x0 + col)) * CC + q * 8;
    const bf16x8_t a00 = *(const bf16x8_t*)(fc);                 // y0, k 0..31
    const bf16x8_t a01 = *(const bf16x8_t*)(fc + 32);            // y0, k 32..63
    const bf16x8_t a10 = *(const bf16x8_t*)(fc + (size_t)WW * CC);      // y0+1
    const bf16x8_t a11 = *(const bf16x8_t*)(fc + (size_t)WW * CC + 32);

    f32x4_t acc[2][3][2];
#pragma unroll
    for (int p = 0; p < 2; ++p)
#pragma unroll
        for (int d = 0; d < 3; ++d)
#pragma unroll
            for (int nt = 0; nt < 2; ++nt)
#pragma unroll
                for (int k = 0; k < 4; ++k) acc[p][d][nt][k] = 0.f;

    // ---- padded rows y0+d0 .. y0+d0+3 feed both y-parts
#pragma unroll
    for (int rr = 0; rr < 4; ++rr) {
        const unsigned short* srow = Sp + ((size_t)b * PH + (y0 + d0 + rr)) * PW * CC;
#pragma unroll
        for (int nt = 0; nt < 2; ++nt) {
            int xp = x0 + col + 16 * nt;
            xp = xp > (PW - 1) ? (PW - 1) : xp;   // clamped lanes never enter the band
            const unsigned short* p = srow + (size_t)xp * CC + q * 8;
            const bf16x8_t b0 = *(const bf16x8_t*)(p);
            const bf16x8_t b1 = *(const bf16x8_t*)(p + 32);
            if (rr < 3) {
                acc[0][rr][nt] = __builtin_amdgcn_mfma_f32_16x16x32_bf16(a00, b0, acc[0][rr][nt], 0, 0, 0);
                acc[0][rr][nt] = __builtin_amdgcn_mfma_f32_16x16x32_bf16(a01, b1, acc[0][rr][nt], 0, 0, 0);
            }
            if (rr >= 1) {
                acc[1][rr - 1][nt] = __builtin_amdgcn_mfma_f32_16x16x32_bf16(a10, b0, acc[1][rr - 1][nt], 0, 0, 0);
                acc[1][rr - 1][nt] = __builtin_amdgcn_mfma_f32_16x16x32_bf16(a11, b1, acc[1][rr - 1][nt], 0, 0, 0);
            }
        }
    }

    // ---- epilogue per y-part: band-extract -> per-wave LDS -> float4 stores
    const float scale = 1.0f / 64.0f;
    float* my = ebuf[wave];
#pragma unroll
    for (int p = 0; p < 2; ++p) {
#pragma unroll
        for (int dyi = 0; dyi < 3; ++dyi)
#pragma unroll
            for (int nt = 0; nt < 2; ++nt)
#pragma unroll
                for (int k = 0; k < 4; ++k) {
                    int m  = 4 * q + k;
                    int dx = col + 16 * nt - m;
                    if (dx >= 0 && dx <= 8)
                        my[(dyi * 9 + dx) * ESTV + m] = acc[p][dyi][nt][k] * scale;
                }
        // in-wave DS ordering: per-wave staging needs no barrier
        float* ob = out + ((size_t)b * NDISP + d0 * 9) * HWSZ + (size_t)(y0 + p) * WW + x0;
        // 27 disp-rows x 16 floats = 108 float4, 2 rounds
#pragma unroll
        for (int rnd = 0; rnd < 2; ++rnd) {
            int idx = rnd * 64 + lane;
            if (idx < 108) {
                int d  = idx >> 2;
                int m4 = (idx & 3) * 4;
                *(float4*)(ob + (size_t)d * HWSZ + m4) = *(const float4*)(my + d * ESTV + m4);
            }
        }
    }
}

// ---------------- fallback: full-buffer zero (mid path) ----------------
__global__ __launch_bounds__(256) void fill_zero(uint4* __restrict__ p, int n4) {
    int i = blockIdx.x * 256 + threadIdx.x;
    if (i < n4) {
        uint4 z; z.x = 0u; z.y = 0u; z.z = 0u; z.w = 0u;
        p[i] = z;
    }
}

// ---------------- fallback: S fp32 CHW -> bf16 (H+8)(W+8)C, +4 offset ----------------
__global__ __launch_bounds__(256) void conv_pad(const float* __restrict__ S,
                                                unsigned short* __restrict__ Sp) {
    __shared__ float tile[64][65];
    const int tx = threadIdx.x;
    const int ty = threadIdx.y;
    const int x0 = blockIdx.x * 64;
    const int y  = blockIdx.y;
    const int b  = blockIdx.z;

    const float* src = S + (size_t)b * CC * HWSZ + (size_t)y * WW + x0 + tx;
#pragma unroll
    for (int i = 0; i < 16; ++i) {
        int c = ty * 16 + i;
        tile[c][tx] = src[(size_t)c * HWSZ];
    }
    __syncthreads();

    const int t  = ty * 64 + tx;
    const int xx = t >> 2;
    const int cg = (t & 3) * 16;
    unsigned short tmp[16];
#pragma unroll
    for (int i = 0; i < 16; ++i) tmp[i] = f2bf(tile[cg + i][xx]);

    unsigned short* dst = Sp + (((size_t)b * PH + (y + 4)) * PW + (x0 + xx + 4)) * CC + cg;
    uint4 v;
    v.x = (unsigned)tmp[0]  | ((unsigned)tmp[1]  << 16);
    v.y = (unsigned)tmp[2]  | ((unsigned)tmp[3]  << 16);
    v.z = (unsigned)tmp[4]  | ((unsigned)tmp[5]  << 16);
    v.w = (unsigned)tmp[6]  | ((unsigned)tmp[7]  << 16);
    *(uint4*)dst = v;
    v.x = (unsigned)tmp[8]  | ((unsigned)tmp[9]  << 16);
    v.y = (unsigned)tmp[10] | ((unsigned)tmp[11] << 16);
    v.z = (unsigned)tmp[12] | ((unsigned)tmp[13] << 16);
    v.w = (unsigned)tmp[14] | ((unsigned)tmp[15] << 16);
    *(uint4*)(dst + 8) = v;
}

// ---------------- mid fallback: round-2 MFMA kernel (F fp32 direct) ----------------
__global__ __launch_bounds__(256) void corr_mfma(const float* __restrict__ F,
                                                 const unsigned short* __restrict__ Sp,
                                                 float* __restrict__ out) {
    __shared__ float lds[4][NDISP * 16];
    const int tid  = threadIdx.x;
    const int wave = tid >> 6;
    const int lane = tid & 63;
    const int q    = lane >> 4;
    const int col  = lane & 15;
    const int wid = blockIdx.x * 4 + wave;
    const int xt  = wid % 20;
    const int y   = (wid / 20) % HH;
    const int b   = wid / (20 * HH);
    const int x0  = xt * 16;

    bf16x8_t a0, a1;
    const float* fb = F + (size_t)b * CC * HWSZ + (size_t)y * WW + x0 + col;
#pragma unroll
    for (int j = 0; j < 8; ++j) {
        a0[j] = (short)f2bf(fb[(size_t)(q * 8 + j) * HWSZ]);
        a1[j] = (short)f2bf(fb[(size_t)(32 + q * 8 + j) * HWSZ]);
    }
    f32x4_t acc[9][2];
#pragma unroll
    for (int i = 0; i < 9; ++i)
#pragma unroll
        for (int nt = 0; nt < 2; ++nt)
#pragma unroll
            for (int r = 0; r < 4; ++r) acc[i][nt][r] = 0.f;
#pragma unroll
    for (int dyi = 0; dyi < 9; ++dyi) {
        const unsigned short* srow = Sp + ((size_t)b * PH + (y + dyi)) * PW * CC;
#pragma unroll
        for (int nt = 0; nt < 2; ++nt) {
            int xp = x0 + col + 16 * nt;
            xp = xp > (PW - 1) ? (PW - 1) : xp;
            const unsigned short* p = srow + (size_t)xp * CC + q * 8;
            bf16x8_t b0 = *(const bf16x8_t*)(p);
            bf16x8_t b1 = *(const bf16x8_t*)(p + 32);
            acc[dyi][nt] = __builtin_amdgcn_mfma_f32_16x16x32_bf16(a0, b0, acc[dyi][nt], 0, 0, 0);
            acc[dyi][nt] = __builtin_amdgcn_mfma_f32_16x16x32_bf16(a1, b1, acc[dyi][nt], 0, 0, 0);
        }
    }
    float* my = lds[wave];
    const float scale = 1.0f / 64.0f;
#pragma unroll
    for (int dyi = 0; dyi < 9; ++dyi)
#pragma unroll
        for (int nt = 0; nt < 2; ++nt)
#pragma unroll
            for (int r = 0; r < 4; ++r) {
                int m  = 4 * q + r;
                int dx = col + 16 * nt - m;
                if (dx >= 0 && dx <= 8)
                    my[(dyi * 9 + dx) * 16 + m] = acc[dyi][nt][r] * scale;
            }
    __syncthreads();
    float* ob = out + (size_t)b * NDISP * HWSZ + (size_t)y * WW + x0;
#pragma unroll
    for (int rnd = 0; rnd < 21; ++rnd) {
        int idx = rnd * 64 + lane;
        if (rnd < 20 || idx < NDISP * 16) {
            int d = idx >> 4, m = idx & 15;
            ob[(size_t)d * HWSZ + m] = my[idx];
        }
    }
}

// ---------------- last-resort fallback: direct fp32 kernel ----------------
#define MDV      4
#define TILE_X   64
#define TILE_Y   8
#define CH_STAGE 4
#define LDS_ROWS (TILE_Y + 2 * MDV)
#define LDS_COLS (TILE_X + 2 * MDV)

__global__ __launch_bounds__(256, 2)
void corr_direct(const float* __restrict__ first,
                 const float* __restrict__ second,
                 float* __restrict__ out) {
    const int C = 64, H = HH, W = WW;
    const int HW = H * W;
    __shared__ float lds[CH_STAGE][LDS_ROWS * LDS_COLS];
    const int tx = threadIdx.x, ty = threadIdx.y;
    const int tid = ty * 32 + tx;
    const int x_tile = blockIdx.x * TILE_X;
    const int y_tile = blockIdx.y * TILE_Y;
    const int b = blockIdx.z;
    const int x0 = x_tile + 2 * tx;
    const int y  = y_tile + ty;
    const float* fst_b = first  + (size_t)b * C * HW;
    const float* sec_b = second + (size_t)b * C * HW;
    float acc[NDISP][2];
#pragma unroll
    for (int d = 0; d < NDISP; ++d) { acc[d][0] = 0.f; acc[d][1] = 0.f; }
    for (int cb = 0; cb < C; cb += CH_STAGE) {
        __syncthreads();
        const int total = CH_STAGE * LDS_ROWS * LDS_COLS;
#pragma unroll
        for (int k = 0; k < total / 256; ++k) {
            int i = tid + k * 256;
            int c   = i / (LDS_ROWS * LDS_COLS);
            int rem = i - c * (LDS_ROWS * LDS_COLS);
            int r   = rem / LDS_COLS;
            int cl  = rem - r * LDS_COLS;
            int gy = y_tile - MDV + r;
            int gx = x_tile - MDV + cl;
            float v = 0.f;
            if ((unsigned)gy < (unsigned)H && (unsigned)gx < (unsigned)W)
                v = sec_b[(size_t)(cb + c) * HW + gy * W + gx];
            lds[c][rem] = v;
        }
        __syncthreads();
#pragma unroll
        for (int cl = 0; cl < CH_STAGE; ++cl) {
            const int c = cb + cl;
            const float2 f = *(const float2*)&fst_b[(size_t)c * HW + y * W + x0];
#pragma unroll
            for (int r = 0; r < 9; ++r) {
                const float* row = &lds[cl][(ty + r) * LDS_COLS + 2 * tx];
                float w[10];
#pragma unroll
                for (int k = 0; k < 5; ++k) {
                    float2 t2 = *(const float2*)&row[2 * k];
                    w[2 * k] = t2.x; w[2 * k + 1] = t2.y;
                }
#pragma unroll
                for (int dx = 0; dx < 9; ++dx) {
                    acc[r * 9 + dx][0] += f.x * w[dx];
                    acc[r * 9 + dx][1] += f.y * w[dx + 1];
                }
            }
        }
    }
    const float scale = 1.0f / 64.0f;
    float* out_b = out + (size_t)b * NDISP * HW;
#pragma unroll
    for (int d = 0; d < NDISP; ++d) {
        float2 o;
        o.x = acc[d][0] * scale;
        o.y = acc[d][1] * scale;
        *(float2*)&out_b[(size_t)d * HW + y * W + x0] = o;
    }
}

extern "C" void kernel_launch(void* const* d_in, const int* in_sizes, int n_in,
                              void* d_out, int out_size, void* d_ws, size_t ws_size,
                              hipStream_t stream) {
    const float* tenFirst  = (const float*)d_in[0];
    const float* tenSecond = (const float*)d_in[1];
    float* out = (float*)d_out;

    const size_t sp_bytes = (size_t)NB * PH * PW * CC * 2;   // 33.6 MB bf16 padded S
    const size_t fc_bytes = (size_t)NB * HH * WW * CC * 2;   // 31.5 MB bf16 F

    if (ws_size >= sp_bytes + fc_bytes) {
        unsigned short* Sp = (unsigned short*)d_ws;
        unsigned short* Fc = (unsigned short*)((char*)d_ws + sp_bytes);
        conv_both<<<dim3(WW / 64, HH, NB), 256, 0, stream>>>(tenFirst, tenSecond, Fc, Sp);
        corr_mfma_v4<<<5760, 256, 0, stream>>>(Fc, Sp, out);
    } else if (ws_size >= sp_bytes) {
        unsigned short* Sp = (unsigned short*)d_ws;
        const int n4 = (int)(sp_bytes / 16);
        fill_zero<<<(n4 + 255) / 256, 256, 0, stream>>>((uint4*)Sp, n4);
        conv_pad<<<dim3(WW / 64, HH, NB), dim3(64, 4), 0, stream>>>(tenSecond, Sp);
        corr_mfma<<<NB * HH * 20 / 4, 256, 0, stream>>>(tenFirst, Sp, out);
    } else {
        corr_direct<<<dim3(WW / TILE_X, HH / TILE_Y, NB), dim3(32, 8), 0, stream>>>(
            tenFirst, tenSecond, out);
    }
}

// Round 3
// 229.936 us; speedup vs baseline: 1.0943x; 1.0195x over previous
//
#include <hip/hip_runtime.h>
#include <hip/hip_bf16.h>

// ModuleCorrelation as implicit GEMM on MFMA (bf16 in, fp32 acc), v6.
// out[b, dy*9+dx, y, x] = (1/64) sum_c F[b,c,y,x] * S[b,c,y+dy-4,x+dx-4]
//
// v6 changes vs v5 (theory: conv_both was pinned at ~2 TB/s regardless of
// occupancy -> the lever is BYTES; corr read Fc 3x redundantly):
//   - Fc buffer eliminated. corr_v5 converts its A-fragment directly from
//     fp32 F (proven corr_mfma-fallback load pattern), F read exactly 1x.
//   - corr_v5: one wave does all 9 dy in 3 sequential groups; only one
//     group's acc[2][3][2] (48 regs) is live at a time -> occupancy kept.
//     Epilogue after each group. 72 MFMAs/wave, 1920 blocks.
//   - conv_s: S-only conversion (half of conv_both's traffic) + frame zero.
//   - workspace requirement drops to Sp only (33.6 MB).

#define WW   320
#define HH   192
#define CC   64
#define HWSZ (HH * WW)
#define NB   4
#define PW   328   // WW + 8
#define PH   200   // HH + 8
#define NDISP 81
#define ESTV 20    // epilogue stride: mult of 4 for b128, breaks bank conflicts

typedef __attribute__((ext_vector_type(8))) short bf16x8_t;   // 8 bf16 (4 VGPRs)
typedef __attribute__((ext_vector_type(4))) float f32x4_t;    // 4 fp32

static __device__ __forceinline__ unsigned short f2bf(float f) {
    unsigned int u = __float_as_uint(f);
    u += 0x7fffu + ((u >> 16) & 1u);   // round-nearest-even
    return (unsigned short)(u >> 16);
}

static __device__ __forceinline__ unsigned pack2(float a, float b) {
    return (unsigned)f2bf(a) | ((unsigned)f2bf(b) << 16);
}

// ---------------- kernel 1 (v6): S -> Sp bf16 conversion + frame zero ----------
__global__ __launch_bounds__(256, 6)
void conv_s(const float* __restrict__ S,
            unsigned short* __restrict__ Sp) {
    __shared__ float ta[64][65];           // 16.64 KB
    const int t  = threadIdx.x;            // 0..255
    const int x0 = blockIdx.x * 64;
    const int y  = blockIdx.y;
    const int b  = blockIdx.z;

    // ---- pad-frame zeroing (520 of 3840 blocks, one uint4 per thread)
    const int blk = (b * HH + y) * (WW / 64) + blockIdx.x;
    const int gid = blk * 256 + t;
    if (gid < NB * 4160 * 8) {
        int bb = gid / (4160 * 8);
        int r  = gid % (4160 * 8);
        int px = r >> 3;
        int v  = r & 7;
        int row, colp;
        if (px < 2624) {                       // top/bottom strips, full width
            int strip = px / 1312;
            int pp    = px % 1312;
            row  = (strip ? 196 : 0) + pp / 328;
            colp = pp % 328;
        } else {                               // left/right 4-col strips
            int tt2 = px - 2624;
            row  = 4 + (tt2 >> 3);
            int tt = tt2 & 7;
            colp = (tt < 4) ? tt : (320 + tt);
        }
        uint4 z; z.x = 0u; z.y = 0u; z.z = 0u; z.w = 0u;
        *(uint4*)((unsigned short*)Sp + ((((size_t)bb * PH + row) * PW + colp) * 8 + v) * 8) = z;
    }

    // ---- 4 float4 loads, all in flight up front
    const int x4 = t & 15;                 // float4 column 0..15
    const int c0 = t >> 4;                 // base channel 0..15
    const float* ssrc = S + (size_t)b * CC * HWSZ + (size_t)y * WW + x0 + 4 * x4;
    float4 vS[4];
#pragma unroll
    for (int k = 0; k < 4; ++k)
        vS[k] = *(const float4*)(ssrc + (size_t)(c0 + 16 * k) * HWSZ);

    // ---- unpack S -> LDS (bank (c+4*x4+j)%32: 2-way = free)
#pragma unroll
    for (int k = 0; k < 4; ++k) {
        int c = c0 + 16 * k;
        ta[c][4 * x4 + 0] = vS[k].x;
        ta[c][4 * x4 + 1] = vS[k].y;
        ta[c][4 * x4 + 2] = vS[k].z;
        ta[c][4 * x4 + 3] = vS[k].w;
    }
    __syncthreads();

    // ---- convert S -> Sp [PH][PW][C], +4 offset
    const int xx = t >> 2;                 // pixel within tile 0..63
    const int cg = (t & 3) * 16;           // channel group base
    unsigned short* dst = Sp + (((size_t)b * PH + (y + 4)) * PW + (x0 + xx + 4)) * CC + cg;
    uint4 w;
    w.x = pack2(ta[cg + 0][xx],  ta[cg + 1][xx]);
    w.y = pack2(ta[cg + 2][xx],  ta[cg + 3][xx]);
    w.z = pack2(ta[cg + 4][xx],  ta[cg + 5][xx]);
    w.w = pack2(ta[cg + 6][xx],  ta[cg + 7][xx]);
    *(uint4*)dst = w;
    w.x = pack2(ta[cg + 8][xx],  ta[cg + 9][xx]);
    w.y = pack2(ta[cg + 10][xx], ta[cg + 11][xx]);
    w.z = pack2(ta[cg + 12][xx], ta[cg + 13][xx]);
    w.w = pack2(ta[cg + 14][xx], ta[cg + 15][xx]);
    *(uint4*)(dst + 8) = w;
}

// ---------------- kernel 2: MFMA correlation v5 (sequential dy-groups) ----------
// Wave owns (b, y-pair, 16-px x-tile) and ALL 9 dy, processed as 3 sequential
// groups of 3 so only acc[2][3][2] (48 regs) is live. A-fragments converted
// directly from fp32 F (F read exactly once device-wide; no Fc buffer).
// 12 B-row loads x 2 nt x 2 halves = 48 b128 loads feed 72 MFMAs per wave.
__global__ __launch_bounds__(256, 4)
void corr_mfma_v5(const float* __restrict__ F,
                  const unsigned short* __restrict__ Sp,
                  float* __restrict__ out) {
    __shared__ float ebuf[4][27 * ESTV];   // 4 waves x 2.16 KB = 8.64 KB

    const int tid  = threadIdx.x;
    const int wave = tid >> 6;
    const int lane = tid & 63;
    const int q    = lane >> 4;
    const int col  = lane & 15;

    // ---- decode: 1920 blocks = 8 xcd x 4 b x 3 pql x 20 xt
    const int i    = blockIdx.x;
    const int xcd  = i & 7;
    const int j    = i >> 3;              // 0..239
    const int b    = j / 60;
    const int r60  = j % 60;
    const int pql  = r60 / 20;            // 0..2
    const int xt   = r60 % 20;
    const int pq   = xcd * 3 + pql;       // 0..23
    const int yp   = pq * 4 + wave;       // ypair 0..95
    const int y0   = yp * 2;
    const int x0   = xt * 16;

    // ---- A fragments for both y rows, converted from fp32 F on the fly
    const float* fb = F + (size_t)b * CC * HWSZ + (size_t)y0 * WW + x0 + col;
    bf16x8_t a00, a01, a10, a11;
#pragma unroll
    for (int jj = 0; jj < 8; ++jj) {
        a00[jj] = (short)f2bf(fb[(size_t)(q * 8 + jj) * HWSZ]);
        a01[jj] = (short)f2bf(fb[(size_t)(32 + q * 8 + jj) * HWSZ]);
        a10[jj] = (short)f2bf(fb[(size_t)(q * 8 + jj) * HWSZ + WW]);
        a11[jj] = (short)f2bf(fb[(size_t)(32 + q * 8 + jj) * HWSZ + WW]);
    }

    const float scale = 1.0f / 64.0f;
    float* my = ebuf[wave];

    for (int g = 0; g < 3; ++g) {
        const int d0 = g * 3;

        f32x4_t acc[2][3][2];
#pragma unroll
        for (int p = 0; p < 2; ++p)
#pragma unroll
            for (int d = 0; d < 3; ++d)
#pragma unroll
                for (int nt = 0; nt < 2; ++nt)
#pragma unroll
                    for (int k = 0; k < 4; ++k) acc[p][d][nt][k] = 0.f;

        // ---- padded rows y0+d0 .. y0+d0+3 feed both y-parts
#pragma unroll
        for (int rr = 0; rr < 4; ++rr) {
            const unsigned short* srow = Sp + ((size_t)b * PH + (y0 + d0 + rr)) * PW * CC;
#pragma unroll
            for (int nt = 0; nt < 2; ++nt) {
                int xp = x0 + col + 16 * nt;
                xp = xp > (PW - 1) ? (PW - 1) : xp;   // clamped lanes never enter the band
                const unsigned short* p = srow + (size_t)xp * CC + q * 8;
                const bf16x8_t b0 = *(const bf16x8_t*)(p);
                const bf16x8_t b1 = *(const bf16x8_t*)(p + 32);
                if (rr < 3) {
                    acc[0][rr][nt] = __builtin_amdgcn_mfma_f32_16x16x32_bf16(a00, b0, acc[0][rr][nt], 0, 0, 0);
                    acc[0][rr][nt] = __builtin_amdgcn_mfma_f32_16x16x32_bf16(a01, b1, acc[0][rr][nt], 0, 0, 0);
                }
                if (rr >= 1) {
                    acc[1][rr - 1][nt] = __builtin_amdgcn_mfma_f32_16x16x32_bf16(a10, b0, acc[1][rr - 1][nt], 0, 0, 0);
                    acc[1][rr - 1][nt] = __builtin_amdgcn_mfma_f32_16x16x32_bf16(a11, b1, acc[1][rr - 1][nt], 0, 0, 0);
                }
            }
        }

        // ---- epilogue per y-part: band-extract -> per-wave LDS -> float4 stores
        // (in-wave DS ordering makes the cross-group LDS reuse safe: a wave's
        //  writes for group g+1 cannot pass its reads for group g)
#pragma unroll
        for (int p = 0; p < 2; ++p) {
#pragma unroll
            for (int dyi = 0; dyi < 3; ++dyi)
#pragma unroll
                for (int nt = 0; nt < 2; ++nt)
#pragma unroll
                    for (int k = 0; k < 4; ++k) {
                        int m  = 4 * q + k;
                        int dx = col + 16 * nt - m;
                        if (dx >= 0 && dx <= 8)
                            my[(dyi * 9 + dx) * ESTV + m] = acc[p][dyi][nt][k] * scale;
                    }
            float* ob = out + ((size_t)b * NDISP + d0 * 9) * HWSZ + (size_t)(y0 + p) * WW + x0;
            // 27 disp-rows x 16 floats = 108 float4, 2 rounds
#pragma unroll
            for (int rnd = 0; rnd < 2; ++rnd) {
                int idx = rnd * 64 + lane;
                if (idx < 108) {
                    int d  = idx >> 2;
                    int m4 = (idx & 3) * 4;
                    *(float4*)(ob + (size_t)d * HWSZ + m4) = *(const float4*)(my + d * ESTV + m4);
                }
            }
        }
    }
}

// ---------------- last-resort fallback: direct fp32 kernel ----------------
#define MDV      4
#define TILE_X   64
#define TILE_Y   8
#define CH_STAGE 4
#define LDS_ROWS (TILE_Y + 2 * MDV)
#define LDS_COLS (TILE_X + 2 * MDV)

__global__ __launch_bounds__(256, 2)
void corr_direct(const float* __restrict__ first,
                 const float* __restrict__ second,
                 float* __restrict__ out) {
    const int C = 64, H = HH, W = WW;
    const int HW = H * W;
    __shared__ float lds[CH_STAGE][LDS_ROWS * LDS_COLS];
    const int tx = threadIdx.x, ty = threadIdx.y;
    const int tid = ty * 32 + tx;
    const int x_tile = blockIdx.x * TILE_X;
    const int y_tile = blockIdx.y * TILE_Y;
    const int b = blockIdx.z;
    const int x0 = x_tile + 2 * tx;
    const int y  = y_tile + ty;
    const float* fst_b = first  + (size_t)b * C * HW;
    const float* sec_b = second + (size_t)b * C * HW;
    float acc[NDISP][2];
#pragma unroll
    for (int d = 0; d < NDISP; ++d) { acc[d][0] = 0.f; acc[d][1] = 0.f; }
    for (int cb = 0; cb < C; cb += CH_STAGE) {
        __syncthreads();
        const int total = CH_STAGE * LDS_ROWS * LDS_COLS;
#pragma unroll
        for (int k = 0; k < total / 256; ++k) {
            int i = tid + k * 256;
            int c   = i / (LDS_ROWS * LDS_COLS);
            int rem = i - c * (LDS_ROWS * LDS_COLS);
            int r   = rem / LDS_COLS;
            int cl  = rem - r * LDS_COLS;
            int gy = y_tile - MDV + r;
            int gx = x_tile - MDV + cl;
            float v = 0.f;
            if ((unsigned)gy < (unsigned)H && (unsigned)gx < (unsigned)W)
                v = sec_b[(size_t)(cb + c) * HW + gy * W + gx];
            lds[c][rem] = v;
        }
        __syncthreads();
#pragma unroll
        for (int cl = 0; cl < CH_STAGE; ++cl) {
            const int c = cb + cl;
            const float2 f = *(const float2*)&fst_b[(size_t)c * HW + y * W + x0];
#pragma unroll
            for (int r = 0; r < 9; ++r) {
                const float* row = &lds[cl][(ty + r) * LDS_COLS + 2 * tx];
                float w[10];
#pragma unroll
                for (int k = 0; k < 5; ++k) {
                    float2 t2 = *(const float2*)&row[2 * k];
                    w[2 * k] = t2.x; w[2 * k + 1] = t2.y;
                }
#pragma unroll
                for (int dx = 0; dx < 9; ++dx) {
                    acc[r * 9 + dx][0] += f.x * w[dx];
                    acc[r * 9 + dx][1] += f.y * w[dx + 1];
                }
            }
        }
    }
    const float scale = 1.0f / 64.0f;
    float* out_b = out + (size_t)b * NDISP * HW;
#pragma unroll
    for (int d = 0; d < NDISP; ++d) {
        float2 o;
        o.x = acc[d][0] * scale;
        o.y = acc[d][1] * scale;
        *(float2*)&out_b[(size_t)d * HW + y * W + x0] = o;
    }
}

extern "C" void kernel_launch(void* const* d_in, const int* in_sizes, int n_in,
                              void* d_out, int out_size, void* d_ws, size_t ws_size,
                              hipStream_t stream) {
    const float* tenFirst  = (const float*)d_in[0];
    const float* tenSecond = (const float*)d_in[1];
    float* out = (float*)d_out;

    const size_t sp_bytes = (size_t)NB * PH * PW * CC * 2;   // 33.6 MB bf16 padded S

    if (ws_size >= sp_bytes) {
        unsigned short* Sp = (unsigned short*)d_ws;
        conv_s<<<dim3(WW / 64, HH, NB), 256, 0, stream>>>(tenSecond, Sp);
        corr_mfma_v5<<<1920, 256, 0, stream>>>(tenFirst, Sp, out);
    } else {
        corr_direct<<<dim3(WW / TILE_X, HH / TILE_Y, NB), dim3(32, 8), 0, stream>>>(
            tenFirst, tenSecond, out);
    }
}

// Round 5
// 201.193 us; speedup vs baseline: 1.2506x; 1.1429x over previous
//
#include <hip/hip_runtime.h>
#include <hip/hip_bf16.h>

// ModuleCorrelation as implicit GEMM on MFMA (bf16 in, fp32 acc), v7 (resubmit:
// round-4 bench died on container acquire, not on the kernel; code re-audited
// for OOB/race/LDS-size fault vectors, none found).
// out[b, dy*9+dx, y, x] = (1/64) sum_c F[b,c,y,x] * S[b,c,y+dy-4,x+dx-4]
//
// v7 theory: corr_v5 was at the vector-memory DEMAND roofline:
// Sp 369 + F 63 + out 80 = 512 MB demand / 81us = 6.3 TB/s. Cut demand bytes:
//   - corr_mfma_v6: block = (b, ypair, 64-px x-quad); 4 waves share ONE ypair
//     and stage the common 4 Sp rows x 80 px x 64 ch per dy-group into LDS
//     (40 KB, bf16) ONCE per block. Sp demand 369 -> 230 MB.
//   - LDS B-tile XOR-swizzled (byte ^= (px&7)<<4): px stride is 128 B, which
//     without swizzle is a 32-way bank conflict on ds_read_b128 (G4 trap).
//   - conv_s unchanged (~35us, byte-bound).

#define WW   320
#define HH   192
#define CC   64
#define HWSZ (HH * WW)
#define NB   4
#define PW   328   // WW + 8
#define PH   200   // HH + 8
#define NDISP 81
#define ESTV 20    // epilogue stride: mult of 4 for b128, breaks bank conflicts
#define QWPX 80    // staged window px per block (64 outputs + 16 halo)

typedef __attribute__((ext_vector_type(8))) short bf16x8_t;   // 8 bf16 (4 VGPRs)
typedef __attribute__((ext_vector_type(4))) float f32x4_t;    // 4 fp32

static __device__ __forceinline__ unsigned short f2bf(float f) {
    unsigned int u = __float_as_uint(f);
    u += 0x7fffu + ((u >> 16) & 1u);   // round-nearest-even
    return (unsigned short)(u >> 16);
}

static __device__ __forceinline__ unsigned pack2(float a, float b) {
    return (unsigned)f2bf(a) | ((unsigned)f2bf(b) << 16);
}

// ---------------- kernel 1: S -> Sp bf16 conversion + frame zero ----------
__global__ __launch_bounds__(256, 6)
void conv_s(const float* __restrict__ S,
            unsigned short* __restrict__ Sp) {
    __shared__ float ta[64][65];           // 16.64 KB
    const int t  = threadIdx.x;            // 0..255
    const int x0 = blockIdx.x * 64;
    const int y  = blockIdx.y;
    const int b  = blockIdx.z;

    // ---- pad-frame zeroing (520 of 3840 blocks, one uint4 per thread)
    const int blk = (b * HH + y) * (WW / 64) + blockIdx.x;
    const int gid = blk * 256 + t;
    if (gid < NB * 4160 * 8) {
        int bb = gid / (4160 * 8);
        int r  = gid % (4160 * 8);
        int px = r >> 3;
        int v  = r & 7;
        int row, colp;
        if (px < 2624) {                       // top/bottom strips, full width
            int strip = px / 1312;
            int pp    = px % 1312;
            row  = (strip ? 196 : 0) + pp / 328;
            colp = pp % 328;
        } else {                               // left/right 4-col strips
            int tt2 = px - 2624;
            row  = 4 + (tt2 >> 3);
            int tt = tt2 & 7;
            colp = (tt < 4) ? tt : (320 + tt);
        }
        uint4 z; z.x = 0u; z.y = 0u; z.z = 0u; z.w = 0u;
        *(uint4*)((unsigned short*)Sp + ((((size_t)bb * PH + row) * PW + colp) * 8 + v) * 8) = z;
    }

    // ---- 4 float4 loads, all in flight up front
    const int x4 = t & 15;                 // float4 column 0..15
    const int c0 = t >> 4;                 // base channel 0..15
    const float* ssrc = S + (size_t)b * CC * HWSZ + (size_t)y * WW + x0 + 4 * x4;
    float4 vS[4];
#pragma unroll
    for (int k = 0; k < 4; ++k)
        vS[k] = *(const float4*)(ssrc + (size_t)(c0 + 16 * k) * HWSZ);

    // ---- unpack S -> LDS (bank (c+4*x4+j)%32: 2-way = free)
#pragma unroll
    for (int k = 0; k < 4; ++k) {
        int c = c0 + 16 * k;
        ta[c][4 * x4 + 0] = vS[k].x;
        ta[c][4 * x4 + 1] = vS[k].y;
        ta[c][4 * x4 + 2] = vS[k].z;
        ta[c][4 * x4 + 3] = vS[k].w;
    }
    __syncthreads();

    // ---- convert S -> Sp [PH][PW][C], +4 offset
    const int xx = t >> 2;                 // pixel within tile 0..63
    const int cg = (t & 3) * 16;           // channel group base
    unsigned short* dst = Sp + (((size_t)b * PH + (y + 4)) * PW + (x0 + xx + 4)) * CC + cg;
    uint4 w;
    w.x = pack2(ta[cg + 0][xx],  ta[cg + 1][xx]);
    w.y = pack2(ta[cg + 2][xx],  ta[cg + 3][xx]);
    w.z = pack2(ta[cg + 4][xx],  ta[cg + 5][xx]);
    w.w = pack2(ta[cg + 6][xx],  ta[cg + 7][xx]);
    *(uint4*)dst = w;
    w.x = pack2(ta[cg + 8][xx],  ta[cg + 9][xx]);
    w.y = pack2(ta[cg + 10][xx], ta[cg + 11][xx]);
    w.z = pack2(ta[cg + 12][xx], ta[cg + 13][xx]);
    w.w = pack2(ta[cg + 14][xx], ta[cg + 15][xx]);
    *(uint4*)(dst + 8) = w;
}

// ---------------- kernel 2: MFMA correlation v6 (block-staged B, x-quads) -----
// Block = (b, ypair, 64-px quad). 4 waves own 4 adjacent 16-px tiles, all 9 dy
// in 3 sequential groups. Per group the block stages the shared 4 Sp rows x
// 80 px x 64 ch into LDS once (40 KB, XOR-swizzled), then each wave runs its
// 24 MFMAs off LDS. A-fragments converted from fp32 F directly (F read 1x).
__global__ __launch_bounds__(256, 3)
void corr_mfma_v6(const float* __restrict__ F,
                  const unsigned short* __restrict__ Sp,
                  float* __restrict__ out) {
    __shared__ unsigned short sbuf[4 * QWPX * CC];   // 40.96 KB staged B tile
    __shared__ float ebuf[4][27 * ESTV];             // 8.64 KB epilogue staging

    const int t    = threadIdx.x;
    const int wave = t >> 6;
    const int lane = t & 63;
    const int q    = lane >> 4;
    const int col  = lane & 15;

    // ---- decode: 1920 blocks = 8 xcd x 4 b x 12 ypl x 5 quad
    const int i    = blockIdx.x;
    const int xcd  = i & 7;
    const int j    = i >> 3;              // 0..239
    const int b    = j / 60;
    const int r60  = j % 60;
    const int ypl  = r60 / 5;             // 0..11
    const int quad = r60 % 5;             // 0..4
    const int yp   = xcd * 12 + ypl;      // ypair 0..95
    const int y0   = yp * 2;
    const int x0b  = quad * 64;           // block x base
    const int x0   = x0b + wave * 16;     // wave's output tile base

    // ---- A fragments for both y rows, converted from fp32 F on the fly
    const float* fb = F + (size_t)b * CC * HWSZ + (size_t)y0 * WW + x0 + col;
    bf16x8_t a00, a01, a10, a11;
#pragma unroll
    for (int jj = 0; jj < 8; ++jj) {
        a00[jj] = (short)f2bf(fb[(size_t)(q * 8 + jj) * HWSZ]);
        a01[jj] = (short)f2bf(fb[(size_t)(32 + q * 8 + jj) * HWSZ]);
        a10[jj] = (short)f2bf(fb[(size_t)(q * 8 + jj) * HWSZ + WW]);
        a11[jj] = (short)f2bf(fb[(size_t)(32 + q * 8 + jj) * HWSZ + WW]);
    }

    const float scale = 1.0f / 64.0f;
    float* my = ebuf[wave];
    const unsigned short* spb = Sp + (size_t)b * PH * PW * CC;

    for (int g = 0; g < 3; ++g) {
        const int d0 = g * 3;

        // ---- stage 4 rows x 80 px x 64 ch of Sp into LDS (XOR-swizzled)
        // 40960 B / (256 thr x 16 B) = 10 b128 chunks per thread; coalesced.
#pragma unroll
        for (int k = 0; k < 10; ++k) {
            int idx   = t + 256 * k;
            int chunk = idx & 7;          // 16-B chunk within a px (8 ch)
            int pxl   = idx >> 3;         // 0..319 linear (rr*80+px)
            int rr    = pxl / QWPX;
            int px    = pxl % QWPX;
            int xp    = x0b + px;
            xp = xp > (PW - 1) ? (PW - 1) : xp;   // clamped px only feed dx>8 (discarded)
            const unsigned short* src =
                spb + ((size_t)(y0 + d0 + rr) * PW + xp) * CC + chunk * 8;
            bf16x8_t v = *(const bf16x8_t*)src;
            int lofs = ((pxl * 128) + chunk * 16) ^ ((px & 7) << 4);
            *(bf16x8_t*)((char*)sbuf + lofs) = v;
        }
        __syncthreads();

        f32x4_t acc[2][3][2];
#pragma unroll
        for (int p = 0; p < 2; ++p)
#pragma unroll
            for (int d = 0; d < 3; ++d)
#pragma unroll
                for (int nt = 0; nt < 2; ++nt)
#pragma unroll
                    for (int k = 0; k < 4; ++k) acc[p][d][nt][k] = 0.f;

        // ---- MFMAs off the staged LDS tile
#pragma unroll
        for (int rr = 0; rr < 4; ++rr) {
#pragma unroll
            for (int nt = 0; nt < 2; ++nt) {
                int px   = wave * 16 + col + 16 * nt;     // 0..79, no clamp needed
                int base = ((rr * QWPX + px) * 128) ^ ((px & 7) << 4);
                const bf16x8_t b0 = *(const bf16x8_t*)((char*)sbuf + (base ^ (q * 16)));
                const bf16x8_t b1 = *(const bf16x8_t*)((char*)sbuf + (base ^ ((q + 4) * 16)));
                if (rr < 3) {
                    acc[0][rr][nt] = __builtin_amdgcn_mfma_f32_16x16x32_bf16(a00, b0, acc[0][rr][nt], 0, 0, 0);
                    acc[0][rr][nt] = __builtin_amdgcn_mfma_f32_16x16x32_bf16(a01, b1, acc[0][rr][nt], 0, 0, 0);
                }
                if (rr >= 1) {
                    acc[1][rr - 1][nt] = __builtin_amdgcn_mfma_f32_16x16x32_bf16(a10, b0, acc[1][rr - 1][nt], 0, 0, 0);
                    acc[1][rr - 1][nt] = __builtin_amdgcn_mfma_f32_16x16x32_bf16(a11, b1, acc[1][rr - 1][nt], 0, 0, 0);
                }
            }
        }
        __syncthreads();   // all waves done with sbuf before next group restages

        // ---- epilogue per y-part: band-extract -> per-wave LDS -> float4 stores
        // (touches only ebuf, not sbuf; all sbuf reads completed before the
        //  barrier above, so next group's staging cannot race them)
#pragma unroll
        for (int p = 0; p < 2; ++p) {
#pragma unroll
            for (int dyi = 0; dyi < 3; ++dyi)
#pragma unroll
                for (int nt = 0; nt < 2; ++nt)
#pragma unroll
                    for (int k = 0; k < 4; ++k) {
                        int m  = 4 * q + k;
                        int dx = col + 16 * nt - m;
                        if (dx >= 0 && dx <= 8)
                            my[(dyi * 9 + dx) * ESTV + m] = acc[p][dyi][nt][k] * scale;
                    }
            float* ob = out + ((size_t)b * NDISP + d0 * 9) * HWSZ + (size_t)(y0 + p) * WW + x0;
            // 27 disp-rows x 16 floats = 108 float4, 2 rounds
#pragma unroll
            for (int rnd = 0; rnd < 2; ++rnd) {
                int idx = rnd * 64 + lane;
                if (idx < 108) {
                    int d  = idx >> 2;
                    int m4 = (idx & 3) * 4;
                    *(float4*)(ob + (size_t)d * HWSZ + m4) = *(const float4*)(my + d * ESTV + m4);
                }
            }
        }
    }
}

// ---------------- last-resort fallback: direct fp32 kernel ----------------
#define MDV      4
#define TILE_X   64
#define TILE_Y   8
#define CH_STAGE 4
#define LDS_ROWS (TILE_Y + 2 * MDV)
#define LDS_COLS (TILE_X + 2 * MDV)

__global__ __launch_bounds__(256, 2)
void corr_direct(const float* __restrict__ first,
                 const float* __restrict__ second,
                 float* __restrict__ out) {
    const int C = 64, H = HH, W = WW;
    const int HW = H * W;
    __shared__ float lds[CH_STAGE][LDS_ROWS * LDS_COLS];
    const int tx = threadIdx.x, ty = threadIdx.y;
    const int tid = ty * 32 + tx;
    const int x_tile = blockIdx.x * TILE_X;
    const int y_tile = blockIdx.y * TILE_Y;
    const int b = blockIdx.z;
    const int x0 = x_tile + 2 * tx;
    const int y  = y_tile + ty;
    const float* fst_b = first  + (size_t)b * C * HW;
    const float* sec_b = second + (size_t)b * C * HW;
    float acc[NDISP][2];
#pragma unroll
    for (int d = 0; d < NDISP; ++d) { acc[d][0] = 0.f; acc[d][1] = 0.f; }
    for (int cb = 0; cb < C; cb += CH_STAGE) {
        __syncthreads();
        const int total = CH_STAGE * LDS_ROWS * LDS_COLS;
#pragma unroll
        for (int k = 0; k < total / 256; ++k) {
            int i = tid + k * 256;
            int c   = i / (LDS_ROWS * LDS_COLS);
            int rem = i - c * (LDS_ROWS * LDS_COLS);
            int r   = rem / LDS_COLS;
            int cl  = rem - r * LDS_COLS;
            int gy = y_tile - MDV + r;
            int gx = x_tile - MDV + cl;
            float v = 0.f;
            if ((unsigned)gy < (unsigned)H && (unsigned)gx < (unsigned)W)
                v = sec_b[(size_t)(cb + c) * HW + gy * W + gx];
            lds[c][rem] = v;
        }
        __syncthreads();
#pragma unroll
        for (int cl = 0; cl < CH_STAGE; ++cl) {
            const int c = cb + cl;
            const float2 f = *(const float2*)&fst_b[(size_t)c * HW + y * W + x0];
#pragma unroll
            for (int r = 0; r < 9; ++r) {
                const float* row = &lds[cl][(ty + r) * LDS_COLS + 2 * tx];
                float w[10];
#pragma unroll
                for (int k = 0; k < 5; ++k) {
                    float2 t2 = *(const float2*)&row[2 * k];
                    w[2 * k] = t2.x; w[2 * k + 1] = t2.y;
                }
#pragma unroll
                for (int dx = 0; dx < 9; ++dx) {
                    acc[r * 9 + dx][0] += f.x * w[dx];
                    acc[r * 9 + dx][1] += f.y * w[dx + 1];
                }
            }
        }
    }
    const float scale = 1.0f / 64.0f;
    float* out_b = out + (size_t)b * NDISP * HW;
#pragma unroll
    for (int d = 0; d < NDISP; ++d) {
        float2 o;
        o.x = acc[d][0] * scale;
        o.y = acc[d][1] * scale;
        *(float2*)&out_b[(size_t)d * HW + y * W + x0] = o;
    }
}

extern "C" void kernel_launch(void* const* d_in, const int* in_sizes, int n_in,
                              void* d_out, int out_size, void* d_ws, size_t ws_size,
                              hipStream_t stream) {
    const float* tenFirst  = (const float*)d_in[0];
    const float* tenSecond = (const float*)d_in[1];
    float* out = (float*)d_out;

    const size_t sp_bytes = (size_t)NB * PH * PW * CC * 2;   // 33.6 MB bf16 padded S

    if (ws_size >= sp_bytes) {
        unsigned short* Sp = (unsigned short*)d_ws;
        conv_s<<<dim3(WW / 64, HH, NB), 256, 0, stream>>>(tenSecond, Sp);
        corr_mfma_v6<<<1920, 256, 0, stream>>>(tenFirst, Sp, out);
    } else {
        corr_direct<<<dim3(WW / TILE_X, HH / TILE_Y, NB), dim3(32, 8), 0, stream>>>(
            tenFirst, tenSecond, out);
    }
}